// Round 5
// baseline (261.199 us; speedup 1.0000x reference)
//
#include <hip/hip_runtime.h>

// Attention block: x[2,2048,1024] fp32, w_qkv[3072,1024], w_out[1024,1024], b_out[1024]
// bf16 MFMA GEMMs + flash attention.
// Round 5: flash restructured for wave-parallelism — 512-thread blocks (16 waves/CU),
// Q/V/K-fragments: Q and V loaded DIRECTLY global->VGPR (16B contiguous in their
// layouts), only K tile LDS-staged (dbuf DMA, 1 barrier/kt), P wave-private stride-68.
// gemm_out retiled 128x64 (grid 256 -> 512, was 1 block/CU).

typedef __attribute__((ext_vector_type(4))) float f32x4;
typedef __attribute__((ext_vector_type(8))) __bf16 bf16x8;
typedef unsigned short u16;

#define DEV static __device__ __forceinline__

DEV u16 f2bf(float x) {  // RNE float->bf16 (epilogues only)
  union { float f; unsigned u; } c; c.f = x;
  unsigned r = c.u + 0x7FFFu + ((c.u >> 16) & 1u);
  return (u16)(r >> 16);
}

DEV void gld16(const void* g, void* l) {  // async global->LDS, 16B/lane
  __builtin_amdgcn_global_load_lds((__attribute__((address_space(1))) void*)g,
                                   (__attribute__((address_space(3))) void*)l, 16, 0, 0);
}

// Fused fp32->bf16 convert for all three tensors (one dispatch).
__global__ __launch_bounds__(256) void cvt_all_kernel(const float* __restrict__ x,
                                                      const float* __restrict__ wq,
                                                      const float* __restrict__ wo,
                                                      u16* __restrict__ xo,
                                                      u16* __restrict__ wqo,
                                                      u16* __restrict__ woo) {
  int t = blockIdx.x * 256 + threadIdx.x;
  const float* in; u16* out; int i;
  if (t < 1048576)       { in = x;  out = xo;  i = t; }
  else if (t < 1835008)  { in = wq; out = wqo; i = t - 1048576; }
  else                   { in = wo; out = woo; i = t - 1835008; }
  float4 v = ((const float4*)in)[i];
  uint2 o;
  o.x = (unsigned)f2bf(v.x) | ((unsigned)f2bf(v.y) << 16);
  o.y = (unsigned)f2bf(v.z) | ((unsigned)f2bf(v.w) << 16);
  ((uint2*)out)[i] = o;
}

// C = A[M,K] * B[N,K]^T, 128x128 tile, BK=32, 4 waves of 64x64, bf16 MFMA.
// Epilogue: scatter to q/k/v buffers [B=2,H=16,L=2048,Dh=64] bf16.
// Q is pre-scaled by scale*log2(e) so flash can exp2 the raw MFMA output.
__global__ __launch_bounds__(256) void gemm_qkv_kernel(const u16* __restrict__ A,
                                                       const u16* __restrict__ Bw,
                                                       u16* __restrict__ qb,
                                                       u16* __restrict__ kb,
                                                       u16* __restrict__ vb) {
  __shared__ alignas(16) u16 As[128 * 32];
  __shared__ alignas(16) u16 Bs[128 * 32];
  const int K = 1024;
  int tid = threadIdx.x, wave = tid >> 6, lane = tid & 63, quad = lane >> 4, l15 = lane & 15;
  int m0 = blockIdx.y * 128, n0 = blockIdx.x * 128;
  f32x4 z = {0.f, 0.f, 0.f, 0.f};
  f32x4 acc[4][4];
  for (int i = 0; i < 4; i++) for (int j = 0; j < 4; j++) acc[i][j] = z;
  int r0 = tid >> 2, ko = (tid & 3) * 8;
  const u16* ga0 = A + (m0 + r0) * K + ko;
  const u16* ga1 = A + (m0 + r0 + 64) * K + ko;
  const u16* gb0 = Bw + (n0 + r0) * K + ko;
  const u16* gb1 = Bw + (n0 + r0 + 64) * K + ko;
  u16 *la0 = &As[tid * 8], *la1 = &As[(256 + tid) * 8];
  u16 *lb0 = &Bs[tid * 8], *lb1 = &Bs[(256 + tid) * 8];
  int ar = (wave & 1) * 64, bc = (wave >> 1) * 64;
  for (int k0 = 0; k0 < K; k0 += 32) {
    gld16(ga0 + k0, la0); gld16(ga1 + k0, la1);
    gld16(gb0 + k0, lb0); gld16(gb1 + k0, lb1);
    __syncthreads();
    bf16x8 af[4], bfr[4];
    for (int i = 0; i < 4; i++) af[i]  = *(const bf16x8*)&As[(ar + i * 16 + l15) * 32 + quad * 8];
    for (int j = 0; j < 4; j++) bfr[j] = *(const bf16x8*)&Bs[(bc + j * 16 + l15) * 32 + quad * 8];
    for (int i = 0; i < 4; i++)
      for (int j = 0; j < 4; j++)
        acc[i][j] = __builtin_amdgcn_mfma_f32_16x16x32_bf16(af[i], bfr[j], acc[i][j], 0, 0, 0);
    __syncthreads();
  }
  int which = n0 >> 10;  // block-uniform: 0=q 1=k 2=v
  u16* dst = which == 0 ? qb : (which == 1 ? kb : vb);
  float qs = which == 0 ? 0.045112882054311f : 1.0f;  // (1/32)*log2(e)
  for (int i = 0; i < 4; i++)
    for (int j = 0; j < 4; j++) {
      int o = n0 + bc + j * 16 + l15;
      int h = (o & 1023) >> 6, d = o & 63;
      for (int r = 0; r < 4; r++) {
        int m = m0 + ar + i * 16 + quad * 4 + r;
        int b = m >> 11, l = m & 2047;
        dst[((b * 16 + h) * 2048 + l) * 64 + d] = f2bf(acc[i][j][r] * qs);
      }
    }
}

// v[bh][l][d] -> vt[bh][d][l]
__global__ __launch_bounds__(256) void transpose_v_kernel(const u16* __restrict__ vb,
                                                          u16* __restrict__ vtb) {
  __shared__ alignas(16) u16 T[64 * 72];
  int lt = blockIdx.x, bh = blockIdx.y;
  int t = threadIdx.x;
  for (int ld = 0; ld < 2; ld++) {
    int idx = ld * 256 + t;
    int l = idx >> 3, d0 = (idx & 7) * 8;
    uint4 v = *(const uint4*)(vb + (bh * 2048 + lt * 64 + l) * 64 + d0);
    *(uint4*)&T[l * 72 + d0] = v;
  }
  __syncthreads();
  for (int ld = 0; ld < 2; ld++) {
    int idx = ld * 256 + t;
    int d = idx >> 3, l0 = (idx & 7) * 8;
    union { u16 us[8]; uint4 v; } tmp;
    for (int i2 = 0; i2 < 8; i2++) tmp.us[i2] = T[(l0 + i2) * 72 + d];
    *(uint4*)(vtb + (bh * 64 + d) * 2048 + lt * 64 + l0) = tmp.v;
  }
}

// Flash attention v2: 512 threads = 8 waves, 16 q-rows per wave.
// K tile: LDS double-buffered via DMA (XOR-swizzled source), 1 barrier/kt.
// Q frags (once) and V frags (per kt): direct global->VGPR dwordx4 loads
// (16B-contiguous in qb[l][64] / vtb[d][2048] layouts) — no LDS, no barrier.
// P: wave-private LDS slab, stride 68 (2-way-free b16 writes, uniform b128 reads).
__global__ __launch_bounds__(512, 4) void flash_kernel(const u16* __restrict__ qb,
                                                       const u16* __restrict__ kb,
                                                       const u16* __restrict__ vtb,
                                                       u16* __restrict__ ob) {
  __shared__ alignas(16) u16 Ks[2][64 * 64];
  __shared__ alignas(16) u16 Ps[128 * 68];
  int qt = blockIdx.x, bh = blockIdx.y;
  int b = bh >> 4, h = bh & 15;
  int tid = threadIdx.x, wave = tid >> 6, lane = tid & 63, quad = lane >> 4, l15 = lane & 15;
  int xw = l15 & 7;
  int q0 = qt * 128;
  const u16* qg = qb + (bh * 2048 + q0) * 64;
  const u16* kgb = kb + bh * 2048 * 64;
  const u16* vgb = vtb + bh * 64 * 2048;

  // Q fragments: direct from global (row = wave*16+l15, dims kk*32+quad*8..+7)
  bf16x8 aq[2];
  aq[0] = *(const bf16x8*)(qg + (wave * 16 + l15) * 64 + quad * 8);
  aq[1] = *(const bf16x8*)(qg + (wave * 16 + l15) * 64 + 32 + quad * 8);

  // stage K tile 0 (swizzled source, linear LDS dest)
  {
    int row = tid >> 3, blk = (tid & 7) ^ (row & 7);
    gld16(kgb + row * 64 + blk * 8, &Ks[0][tid * 8]);
  }
  __syncthreads();

  bf16x8 vone;
  for (int e = 0; e < 8; e++) vone[e] = (__bf16)1.0f;
  f32x4 z = {0.f, 0.f, 0.f, 0.f};
  f32x4 o_[4], o4 = z;
  for (int j = 0; j < 4; j++) o_[j] = z;

  int blkA = (quad ^ xw) * 8;        // K frag block offsets (cols 0-31)
  int blkB = ((4 + quad) ^ xw) * 8;  // cols 32-63
  u16* pw = &Ps[(wave * 16 + quad * 4) * 68 + l15];   // P write base (+r*68 + j*16)
  const u16* pr = &Ps[(wave * 16 + l15) * 68];        // P read base (+quad*8 / +32)

  for (int kt = 0; kt < 32; kt++) {
    int cur = kt & 1;
    if (kt < 31) {  // DMA-prefetch next K tile into alternate buffer
      int row = tid >> 3, blk = (tid & 7) ^ (row & 7);
      gld16(kgb + (kt + 1) * 4096 + row * 64 + blk * 8, &Ks[cur ^ 1][tid * 8]);
    }
    // V fragments: direct from global, issued early to cover L2 latency.
    // bv0[j]: B[k=quad*8+jj][n=j*16+l15] = vt[d=j*16+l15][keys kt*64+quad*8..+7]
    bf16x8 bv0[4], bv1[4];
    for (int j = 0; j < 4; j++) {
      const u16* vr = vgb + (j * 16 + l15) * 2048 + kt * 64;
      bv0[j] = *(const bf16x8*)(vr + quad * 8);
      bv1[j] = *(const bf16x8*)(vr + 32 + quad * 8);
    }
    const u16* ks = Ks[cur];
    bf16x8 bk0[4], bk1[4];
    for (int j = 0; j < 4; j++) {
      int ro = (j * 16 + l15) * 64;
      bk0[j] = *(const bf16x8*)&ks[ro + blkA];
      bk1[j] = *(const bf16x8*)&ks[ro + blkB];
    }
    f32x4 s[4];
    for (int j = 0; j < 4; j++) {
      s[j] = __builtin_amdgcn_mfma_f32_16x16x32_bf16(aq[0], bk0[j], z, 0, 0, 0);
      s[j] = __builtin_amdgcn_mfma_f32_16x16x32_bf16(aq[1], bk1[j], s[j], 0, 0, 0);
    }
    // softmax numerator: raw v_exp_f32 (Q pre-scaled), round-half-up bf16 hi-store
    for (int j = 0; j < 4; j++)
      for (int r = 0; r < 4; r++) {
        float p = __builtin_amdgcn_exp2f(s[j][r]);
        unsigned u = __float_as_uint(p) + 0x8000u;
        pw[r * 68 + j * 16] = (u16)(u >> 16);
      }
    // P fragments (wave-private slab; in-wave lgkmcnt ordering suffices)
    bf16x8 ap0 = *(const bf16x8*)&pr[quad * 8];
    bf16x8 ap1 = *(const bf16x8*)&pr[32 + quad * 8];
    for (int j = 0; j < 4; j++) {
      o_[j] = __builtin_amdgcn_mfma_f32_16x16x32_bf16(ap0, bv0[j], o_[j], 0, 0, 0);
      o_[j] = __builtin_amdgcn_mfma_f32_16x16x32_bf16(ap1, bv1[j], o_[j], 0, 0, 0);
    }
    // denominator: row-sum of P via ones-column (MFMA pipe)
    o4 = __builtin_amdgcn_mfma_f32_16x16x32_bf16(ap0, vone, o4, 0, 0, 0);
    o4 = __builtin_amdgcn_mfma_f32_16x16x32_bf16(ap1, vone, o4, 0, 0, 0);
    __syncthreads();  // drains next-K DMA; fences cur K buffer reuse
  }
  for (int j = 0; j < 4; j++) {
    int c = h * 64 + j * 16 + l15;
    for (int r = 0; r < 4; r++) {
      int q = q0 + wave * 16 + quad * 4 + r;
      ob[(b * 2048 + q) * 1024 + c] = f2bf(o_[j][r] / o4[r]);
    }
  }
}

// out[M,N] = A[M,K] * B[N,K]^T + bias[N], fp32 out. 128x64 tile -> grid 512 (2/CU).
__global__ __launch_bounds__(256) void gemm_out_kernel(const u16* __restrict__ A,
                                                       const u16* __restrict__ Bw,
                                                       const float* __restrict__ bias,
                                                       float* __restrict__ out) {
  __shared__ alignas(16) u16 As[128 * 32];
  __shared__ alignas(16) u16 Bs[64 * 32];
  const int K = 1024;
  int tid = threadIdx.x, wave = tid >> 6, lane = tid & 63, quad = lane >> 4, l15 = lane & 15;
  int m0 = blockIdx.y * 128, n0 = blockIdx.x * 64;
  f32x4 z = {0.f, 0.f, 0.f, 0.f};
  f32x4 acc[4][2];
  for (int i = 0; i < 4; i++) for (int j = 0; j < 2; j++) acc[i][j] = z;
  int r0 = tid >> 2, ko = (tid & 3) * 8;
  const u16* ga0 = A + (m0 + r0) * K + ko;
  const u16* ga1 = A + (m0 + r0 + 64) * K + ko;
  const u16* gb0 = Bw + (n0 + r0) * K + ko;  // r0 < 64 rows of B
  u16 *la0 = &As[tid * 8], *la1 = &As[(256 + tid) * 8];
  u16 *lb0 = &Bs[tid * 8];
  int ar = (wave & 1) * 64, bc = (wave >> 1) * 32;
  for (int k0 = 0; k0 < K; k0 += 32) {
    gld16(ga0 + k0, la0); gld16(ga1 + k0, la1);
    if (tid < 256) gld16(gb0 + k0, lb0);
    __syncthreads();
    bf16x8 af[4], bfr[2];
    for (int i = 0; i < 4; i++) af[i]  = *(const bf16x8*)&As[(ar + i * 16 + l15) * 32 + quad * 8];
    for (int j = 0; j < 2; j++) bfr[j] = *(const bf16x8*)&Bs[(bc + j * 16 + l15) * 32 + quad * 8];
    for (int i = 0; i < 4; i++)
      for (int j = 0; j < 2; j++)
        acc[i][j] = __builtin_amdgcn_mfma_f32_16x16x32_bf16(af[i], bfr[j], acc[i][j], 0, 0, 0);
    __syncthreads();
  }
  for (int i = 0; i < 4; i++)
    for (int j = 0; j < 2; j++) {
      int o = n0 + bc + j * 16 + l15;
      float bo = bias[o];
      for (int r = 0; r < 4; r++) {
        int m = m0 + ar + i * 16 + quad * 4 + r;
        out[m * 1024 + o] = acc[i][j][r] + bo;
      }
    }
}

extern "C" void kernel_launch(void* const* d_in, const int* in_sizes, int n_in,
                              void* d_out, int out_size, void* d_ws, size_t ws_size,
                              hipStream_t stream) {
  const float* x     = (const float*)d_in[0];
  const float* w_qkv = (const float*)d_in[1];
  const float* w_out = (const float*)d_in[2];
  const float* b_out = (const float*)d_in[3];
  float* out = (float*)d_out;
  u16* ws = (u16*)d_ws;
  u16* x_bf    = ws;             // 4194304
  u16* wqkv_bf = ws + 4194304;   // 3145728
  u16* wout_bf = ws + 7340032;   // 1048576
  u16* qb      = ws + 8388608;   // 4194304  [B,H,L,64] (pre-scaled)
  u16* kb      = ws + 12582912;  // 4194304  [B,H,L,64]
  u16* vb      = ws + 16777216;  // 4194304  [B,H,L,64]
  u16* vtb     = ws + 20971520;  // 4194304  [B,H,64,L]
  u16* ob      = ws + 25165824;  // 4194304  [B,L,C]

  cvt_all_kernel<<<8192, 256, 0, stream>>>(x, w_qkv, w_out, x_bf, wqkv_bf, wout_bf);
  gemm_qkv_kernel<<<dim3(24, 32), 256, 0, stream>>>(x_bf, wqkv_bf, qb, kb, vb);
  transpose_v_kernel<<<dim3(32, 32), 256, 0, stream>>>(vb, vtb);
  flash_kernel<<<dim3(16, 32), 512, 0, stream>>>(qb, kb, vtb, ob);
  gemm_out_kernel<<<dim3(16, 32), 256, 0, stream>>>(ob, wout_bf, b_out, out);
}

// Round 6
// 223.203 us; speedup vs baseline: 1.1702x; 1.1702x over previous
//
#include <hip/hip_runtime.h>

// Attention block: x[2,2048,1024] fp32, w_qkv[3072,1024], w_out[1024,1024], b_out[1024]
// bf16 MFMA GEMMs + flash attention.
// Round 6: flash = round-4 phase structure (K AND V LDS-staged dbuf DMA — shared
// across waves) at 512 threads / 16 q-rows per wave -> 16 waves/CU (round-5's
// direct-to-VGPR V loads serialized global latency at VGPR=40; reverted).

typedef __attribute__((ext_vector_type(4))) float f32x4;
typedef __attribute__((ext_vector_type(8))) __bf16 bf16x8;
typedef unsigned short u16;

#define DEV static __device__ __forceinline__

DEV u16 f2bf(float x) {  // RNE float->bf16 (epilogues only)
  union { float f; unsigned u; } c; c.f = x;
  unsigned r = c.u + 0x7FFFu + ((c.u >> 16) & 1u);
  return (u16)(r >> 16);
}

DEV void gld16(const void* g, void* l) {  // async global->LDS, 16B/lane
  __builtin_amdgcn_global_load_lds((__attribute__((address_space(1))) void*)g,
                                   (__attribute__((address_space(3))) void*)l, 16, 0, 0);
}

// Fused fp32->bf16 convert for all three tensors (one dispatch).
__global__ __launch_bounds__(256) void cvt_all_kernel(const float* __restrict__ x,
                                                      const float* __restrict__ wq,
                                                      const float* __restrict__ wo,
                                                      u16* __restrict__ xo,
                                                      u16* __restrict__ wqo,
                                                      u16* __restrict__ woo) {
  int t = blockIdx.x * 256 + threadIdx.x;
  const float* in; u16* out; int i;
  if (t < 1048576)       { in = x;  out = xo;  i = t; }
  else if (t < 1835008)  { in = wq; out = wqo; i = t - 1048576; }
  else                   { in = wo; out = woo; i = t - 1835008; }
  float4 v = ((const float4*)in)[i];
  uint2 o;
  o.x = (unsigned)f2bf(v.x) | ((unsigned)f2bf(v.y) << 16);
  o.y = (unsigned)f2bf(v.z) | ((unsigned)f2bf(v.w) << 16);
  ((uint2*)out)[i] = o;
}

// C = A[M,K] * B[N,K]^T, 128x128 tile, BK=32, 4 waves of 64x64, bf16 MFMA.
// Epilogue: scatter to q/k/v buffers [B=2,H=16,L=2048,Dh=64] bf16.
// Q is pre-scaled by scale*log2(e) so flash can exp2 the raw MFMA output.
__global__ __launch_bounds__(256) void gemm_qkv_kernel(const u16* __restrict__ A,
                                                       const u16* __restrict__ Bw,
                                                       u16* __restrict__ qb,
                                                       u16* __restrict__ kb,
                                                       u16* __restrict__ vb) {
  __shared__ alignas(16) u16 As[128 * 32];
  __shared__ alignas(16) u16 Bs[128 * 32];
  const int K = 1024;
  int tid = threadIdx.x, wave = tid >> 6, lane = tid & 63, quad = lane >> 4, l15 = lane & 15;
  int m0 = blockIdx.y * 128, n0 = blockIdx.x * 128;
  f32x4 z = {0.f, 0.f, 0.f, 0.f};
  f32x4 acc[4][4];
  for (int i = 0; i < 4; i++) for (int j = 0; j < 4; j++) acc[i][j] = z;
  int r0 = tid >> 2, ko = (tid & 3) * 8;
  const u16* ga0 = A + (m0 + r0) * K + ko;
  const u16* ga1 = A + (m0 + r0 + 64) * K + ko;
  const u16* gb0 = Bw + (n0 + r0) * K + ko;
  const u16* gb1 = Bw + (n0 + r0 + 64) * K + ko;
  u16 *la0 = &As[tid * 8], *la1 = &As[(256 + tid) * 8];
  u16 *lb0 = &Bs[tid * 8], *lb1 = &Bs[(256 + tid) * 8];
  int ar = (wave & 1) * 64, bc = (wave >> 1) * 64;
  for (int k0 = 0; k0 < K; k0 += 32) {
    gld16(ga0 + k0, la0); gld16(ga1 + k0, la1);
    gld16(gb0 + k0, lb0); gld16(gb1 + k0, lb1);
    __syncthreads();
    bf16x8 af[4], bfr[4];
    for (int i = 0; i < 4; i++) af[i]  = *(const bf16x8*)&As[(ar + i * 16 + l15) * 32 + quad * 8];
    for (int j = 0; j < 4; j++) bfr[j] = *(const bf16x8*)&Bs[(bc + j * 16 + l15) * 32 + quad * 8];
    for (int i = 0; i < 4; i++)
      for (int j = 0; j < 4; j++)
        acc[i][j] = __builtin_amdgcn_mfma_f32_16x16x32_bf16(af[i], bfr[j], acc[i][j], 0, 0, 0);
    __syncthreads();
  }
  int which = n0 >> 10;  // block-uniform: 0=q 1=k 2=v
  u16* dst = which == 0 ? qb : (which == 1 ? kb : vb);
  float qs = which == 0 ? 0.045112882054311f : 1.0f;  // (1/32)*log2(e)
  for (int i = 0; i < 4; i++)
    for (int j = 0; j < 4; j++) {
      int o = n0 + bc + j * 16 + l15;
      int h = (o & 1023) >> 6, d = o & 63;
      for (int r = 0; r < 4; r++) {
        int m = m0 + ar + i * 16 + quad * 4 + r;
        int b = m >> 11, l = m & 2047;
        dst[((b * 16 + h) * 2048 + l) * 64 + d] = f2bf(acc[i][j][r] * qs);
      }
    }
}

// v[bh][l][d] -> vt[bh][d][l]
__global__ __launch_bounds__(256) void transpose_v_kernel(const u16* __restrict__ vb,
                                                          u16* __restrict__ vtb) {
  __shared__ alignas(16) u16 T[64 * 72];
  int lt = blockIdx.x, bh = blockIdx.y;
  int t = threadIdx.x;
  for (int ld = 0; ld < 2; ld++) {
    int idx = ld * 256 + t;
    int l = idx >> 3, d0 = (idx & 7) * 8;
    uint4 v = *(const uint4*)(vb + (bh * 2048 + lt * 64 + l) * 64 + d0);
    *(uint4*)&T[l * 72 + d0] = v;
  }
  __syncthreads();
  for (int ld = 0; ld < 2; ld++) {
    int idx = ld * 256 + t;
    int d = idx >> 3, l0 = (idx & 7) * 8;
    union { u16 us[8]; uint4 v; } tmp;
    for (int i2 = 0; i2 < 8; i2++) tmp.us[i2] = T[(l0 + i2) * 72 + d];
    *(uint4*)(vtb + (bh * 64 + d) * 2048 + lt * 64 + l0) = tmp.v;
  }
}

// Flash attention v3: 512 threads = 8 waves, 16 q-rows per wave, 128-row q-tile.
// K and V tiles: LDS double-buffered via DMA (XOR-swizzled source), shared by all
// waves, 1 barrier/kt. P: stride-68 slab UNIONED with Q staging. Softmax denom on
// the MFMA pipe via ones-column.
__global__ __launch_bounds__(512, 4) void flash_kernel(const u16* __restrict__ qb,
                                                       const u16* __restrict__ kb,
                                                       const u16* __restrict__ vtb,
                                                       u16* __restrict__ ob) {
  __shared__ alignas(16) u16 Ks[2][64 * 64];
  __shared__ alignas(16) u16 Vts[2][64 * 64];
  __shared__ alignas(16) u16 QP[128 * 68];   // Q staging (first 8192) then P stride-68
  int qt = blockIdx.x, bh = blockIdx.y;
  int b = bh >> 4, h = bh & 15;
  int tid = threadIdx.x, wave = tid >> 6, lane = tid & 63, quad = lane >> 4, l15 = lane & 15;
  int xw = l15 & 7;
  int q0 = qt * 128;
  const u16* qg = qb + (bh * 2048 + q0) * 64;
  const u16* kgb = kb + bh * 2048 * 64;
  const u16* vgb = vtb + bh * 64 * 2048;

  // stage Q (swizzled source) into QP[0..8192)
  for (int it = 0; it < 2; it++) {
    int idx = it * 512 + tid;
    int row = idx >> 3, blk = (idx & 7) ^ (row & 7);
    gld16(qg + row * 64 + blk * 8, &QP[idx * 8]);
  }
  // stage K/V tile 0 into buffer 0 (512 threads x 16B = 8KB each)
  {
    int row = tid >> 3, blk = (tid & 7) ^ (row & 7);
    gld16(kgb + row * 64 + blk * 8, &Ks[0][tid * 8]);
    gld16(vgb + row * 2048 + blk * 8, &Vts[0][tid * 8]);
  }
  __syncthreads();

  // Q fragments (row = wave*16 + l15; row&7 == xw)
  bf16x8 aq[2];
  {
    int row = wave * 16 + l15;
    aq[0] = *(const bf16x8*)&QP[row * 64 + ((quad ^ xw) * 8)];
    aq[1] = *(const bf16x8*)&QP[row * 64 + (((4 + quad) ^ xw) * 8)];
  }
  __syncthreads();  // Q in regs; QP now reusable as P

  bf16x8 vone;
  for (int e = 0; e < 8; e++) vone[e] = (__bf16)1.0f;
  f32x4 z = {0.f, 0.f, 0.f, 0.f};
  f32x4 o_[4], o4 = z;
  for (int j = 0; j < 4; j++) o_[j] = z;

  int blkA = (quad ^ xw) * 8;        // swizzled frag block offsets (cols 0-31)
  int blkB = ((4 + quad) ^ xw) * 8;  // cols 32-63
  u16* pw = &QP[(wave * 16 + quad * 4) * 68 + l15];   // P write base (+r*68 + j*16)
  const u16* pr = &QP[(wave * 16 + l15) * 68];        // P read base (+quad*8 / +32)

  for (int kt = 0; kt < 32; kt++) {
    int cur = kt & 1;
    if (kt < 31) {  // DMA-prefetch next K/V tile into alternate buffer
      int nxt = cur ^ 1;
      int row = tid >> 3, blk = (tid & 7) ^ (row & 7);
      gld16(kgb + (kt + 1) * 4096 + row * 64 + blk * 8, &Ks[nxt][tid * 8]);
      gld16(vgb + row * 2048 + (kt + 1) * 64 + blk * 8, &Vts[nxt][tid * 8]);
    }
    const u16* ks = Ks[cur];
    const u16* vs = Vts[cur];
    bf16x8 bk0[4], bk1[4];
    for (int j = 0; j < 4; j++) {
      int ro = (j * 16 + l15) * 64;
      bk0[j] = *(const bf16x8*)&ks[ro + blkA];
      bk1[j] = *(const bf16x8*)&ks[ro + blkB];
    }
    f32x4 s[4];
    for (int j = 0; j < 4; j++) {
      s[j] = __builtin_amdgcn_mfma_f32_16x16x32_bf16(aq[0], bk0[j], z, 0, 0, 0);
      s[j] = __builtin_amdgcn_mfma_f32_16x16x32_bf16(aq[1], bk1[j], s[j], 0, 0, 0);
    }
    // softmax numerator: raw v_exp_f32 (Q pre-scaled), round-half-up bf16 hi-store
    for (int j = 0; j < 4; j++)
      for (int r = 0; r < 4; r++) {
        float p = __builtin_amdgcn_exp2f(s[j][r]);
        unsigned u = __float_as_uint(p) + 0x8000u;
        pw[r * 68 + j * 16] = (u16)(u >> 16);
      }
    bf16x8 bv0[4], bv1[4];
    for (int j = 0; j < 4; j++) {
      int ro = (j * 16 + l15) * 64;
      bv0[j] = *(const bf16x8*)&vs[ro + blkA];
      bv1[j] = *(const bf16x8*)&vs[ro + blkB];
    }
    // P fragments (wave-private rows; in-wave lgkmcnt ordering suffices)
    bf16x8 ap0 = *(const bf16x8*)&pr[quad * 8];
    bf16x8 ap1 = *(const bf16x8*)&pr[32 + quad * 8];
    for (int j = 0; j < 4; j++) {
      o_[j] = __builtin_amdgcn_mfma_f32_16x16x32_bf16(ap0, bv0[j], o_[j], 0, 0, 0);
      o_[j] = __builtin_amdgcn_mfma_f32_16x16x32_bf16(ap1, bv1[j], o_[j], 0, 0, 0);
    }
    // denominator: row-sum of P via ones-column (MFMA pipe)
    o4 = __builtin_amdgcn_mfma_f32_16x16x32_bf16(ap0, vone, o4, 0, 0, 0);
    o4 = __builtin_amdgcn_mfma_f32_16x16x32_bf16(ap1, vone, o4, 0, 0, 0);
    __syncthreads();  // drains next-tile DMA; fences cur buffers + P reuse
  }
  for (int j = 0; j < 4; j++) {
    int c = h * 64 + j * 16 + l15;
    for (int r = 0; r < 4; r++) {
      int q = q0 + wave * 16 + quad * 4 + r;
      ob[(b * 2048 + q) * 1024 + c] = f2bf(o_[j][r] / o4[r]);
    }
  }
}

// out[M,N] = A[M,K] * B[N,K]^T + bias[N], fp32 out. 128x64 tile -> grid 512 (2/CU).
__global__ __launch_bounds__(256) void gemm_out_kernel(const u16* __restrict__ A,
                                                       const u16* __restrict__ Bw,
                                                       const float* __restrict__ bias,
                                                       float* __restrict__ out) {
  __shared__ alignas(16) u16 As[128 * 32];
  __shared__ alignas(16) u16 Bs[64 * 32];
  const int K = 1024;
  int tid = threadIdx.x, wave = tid >> 6, lane = tid & 63, quad = lane >> 4, l15 = lane & 15;
  int m0 = blockIdx.y * 128, n0 = blockIdx.x * 64;
  f32x4 z = {0.f, 0.f, 0.f, 0.f};
  f32x4 acc[4][2];
  for (int i = 0; i < 4; i++) for (int j = 0; j < 2; j++) acc[i][j] = z;
  int r0 = tid >> 2, ko = (tid & 3) * 8;
  const u16* ga0 = A + (m0 + r0) * K + ko;
  const u16* ga1 = A + (m0 + r0 + 64) * K + ko;
  const u16* gb0 = Bw + (n0 + r0) * K + ko;
  u16 *la0 = &As[tid * 8], *la1 = &As[(256 + tid) * 8];
  u16 *lb0 = &Bs[tid * 8];
  int ar = (wave & 1) * 64, bc = (wave >> 1) * 32;
  for (int k0 = 0; k0 < K; k0 += 32) {
    gld16(ga0 + k0, la0); gld16(ga1 + k0, la1);
    if (r0 < 64) gld16(gb0 + k0, lb0);
    __syncthreads();
    bf16x8 af[4], bfr[2];
    for (int i = 0; i < 4; i++) af[i]  = *(const bf16x8*)&As[(ar + i * 16 + l15) * 32 + quad * 8];
    for (int j = 0; j < 2; j++) bfr[j] = *(const bf16x8*)&Bs[(bc + j * 16 + l15) * 32 + quad * 8];
    for (int i = 0; i < 4; i++)
      for (int j = 0; j < 2; j++)
        acc[i][j] = __builtin_amdgcn_mfma_f32_16x16x32_bf16(af[i], bfr[j], acc[i][j], 0, 0, 0);
    __syncthreads();
  }
  for (int i = 0; i < 4; i++)
    for (int j = 0; j < 2; j++) {
      int o = n0 + bc + j * 16 + l15;
      float bo = bias[o];
      for (int r = 0; r < 4; r++) {
        int m = m0 + ar + i * 16 + quad * 4 + r;
        out[m * 1024 + o] = acc[i][j][r] + bo;
      }
    }
}

extern "C" void kernel_launch(void* const* d_in, const int* in_sizes, int n_in,
                              void* d_out, int out_size, void* d_ws, size_t ws_size,
                              hipStream_t stream) {
  const float* x     = (const float*)d_in[0];
  const float* w_qkv = (const float*)d_in[1];
  const float* w_out = (const float*)d_in[2];
  const float* b_out = (const float*)d_in[3];
  float* out = (float*)d_out;
  u16* ws = (u16*)d_ws;
  u16* x_bf    = ws;             // 4194304
  u16* wqkv_bf = ws + 4194304;   // 3145728
  u16* wout_bf = ws + 7340032;   // 1048576
  u16* qb      = ws + 8388608;   // 4194304  [B,H,L,64] (pre-scaled)
  u16* kb      = ws + 12582912;  // 4194304  [B,H,L,64]
  u16* vb      = ws + 16777216;  // 4194304  [B,H,L,64]
  u16* vtb     = ws + 20971520;  // 4194304  [B,H,64,L]
  u16* ob      = ws + 25165824;  // 4194304  [B,L,C]

  cvt_all_kernel<<<8192, 256, 0, stream>>>(x, w_qkv, w_out, x_bf, wqkv_bf, wout_bf);
  gemm_qkv_kernel<<<dim3(24, 32), 256, 0, stream>>>(x_bf, wqkv_bf, qb, kb, vb);
  transpose_v_kernel<<<dim3(32, 32), 256, 0, stream>>>(vb, vtb);
  flash_kernel<<<dim3(16, 32), 512, 0, stream>>>(qb, kb, vtb, ob);
  gemm_out_kernel<<<dim3(16, 32), 256, 0, stream>>>(ob, wout_bf, b_out, out);
}

// Round 7
// 200.567 us; speedup vs baseline: 1.3023x; 1.1129x over previous
//
#include <hip/hip_runtime.h>

// Attention block: x[2,2048,1024] fp32, w_qkv[3072,1024], w_out[1024,1024], b_out[1024]
// bf16 MFMA GEMMs + flash attention.
// Round 7: flash = 128-thread blocks (2 waves x 32 q-rows), 64-row q-tiles,
// grid 1024 = 4 INDEPENDENT blocks/CU (LDS exactly 40960 B). Lockstep-phase
// overlap comes from independent barrier domains (r6 showed more waves per
// domain regress). P slab stride-64 with XOR block-swizzle keyed on row bits
// {0,2,3}: write addrs fold to 2 lane bases + immediates, b128 reads conflict-free.

typedef __attribute__((ext_vector_type(4))) float f32x4;
typedef __attribute__((ext_vector_type(8))) __bf16 bf16x8;
typedef unsigned short u16;

#define DEV static __device__ __forceinline__

DEV u16 f2bf(float x) {  // RNE float->bf16 (epilogues only)
  union { float f; unsigned u; } c; c.f = x;
  unsigned r = c.u + 0x7FFFu + ((c.u >> 16) & 1u);
  return (u16)(r >> 16);
}

DEV void gld16(const void* g, void* l) {  // async global->LDS, 16B/lane
  __builtin_amdgcn_global_load_lds((__attribute__((address_space(1))) void*)g,
                                   (__attribute__((address_space(3))) void*)l, 16, 0, 0);
}

// Fused fp32->bf16 convert for all three tensors (one dispatch).
__global__ __launch_bounds__(256) void cvt_all_kernel(const float* __restrict__ x,
                                                      const float* __restrict__ wq,
                                                      const float* __restrict__ wo,
                                                      u16* __restrict__ xo,
                                                      u16* __restrict__ wqo,
                                                      u16* __restrict__ woo) {
  int t = blockIdx.x * 256 + threadIdx.x;
  const float* in; u16* out; int i;
  if (t < 1048576)       { in = x;  out = xo;  i = t; }
  else if (t < 1835008)  { in = wq; out = wqo; i = t - 1048576; }
  else                   { in = wo; out = woo; i = t - 1835008; }
  float4 v = ((const float4*)in)[i];
  uint2 o;
  o.x = (unsigned)f2bf(v.x) | ((unsigned)f2bf(v.y) << 16);
  o.y = (unsigned)f2bf(v.z) | ((unsigned)f2bf(v.w) << 16);
  ((uint2*)out)[i] = o;
}

// C = A[M,K] * B[N,K]^T, 128x128 tile, BK=32, 4 waves of 64x64, bf16 MFMA.
// Epilogue: scatter to q/k/v buffers [B=2,H=16,L=2048,Dh=64] bf16.
// Q is pre-scaled by scale*log2(e) so flash can exp2 the raw MFMA output.
__global__ __launch_bounds__(256) void gemm_qkv_kernel(const u16* __restrict__ A,
                                                       const u16* __restrict__ Bw,
                                                       u16* __restrict__ qb,
                                                       u16* __restrict__ kb,
                                                       u16* __restrict__ vb) {
  __shared__ alignas(16) u16 As[128 * 32];
  __shared__ alignas(16) u16 Bs[128 * 32];
  const int K = 1024;
  int tid = threadIdx.x, wave = tid >> 6, lane = tid & 63, quad = lane >> 4, l15 = lane & 15;
  int m0 = blockIdx.y * 128, n0 = blockIdx.x * 128;
  f32x4 z = {0.f, 0.f, 0.f, 0.f};
  f32x4 acc[4][4];
  for (int i = 0; i < 4; i++) for (int j = 0; j < 4; j++) acc[i][j] = z;
  int r0 = tid >> 2, ko = (tid & 3) * 8;
  const u16* ga0 = A + (m0 + r0) * K + ko;
  const u16* ga1 = A + (m0 + r0 + 64) * K + ko;
  const u16* gb0 = Bw + (n0 + r0) * K + ko;
  const u16* gb1 = Bw + (n0 + r0 + 64) * K + ko;
  u16 *la0 = &As[tid * 8], *la1 = &As[(256 + tid) * 8];
  u16 *lb0 = &Bs[tid * 8], *lb1 = &Bs[(256 + tid) * 8];
  int ar = (wave & 1) * 64, bc = (wave >> 1) * 64;
  for (int k0 = 0; k0 < K; k0 += 32) {
    gld16(ga0 + k0, la0); gld16(ga1 + k0, la1);
    gld16(gb0 + k0, lb0); gld16(gb1 + k0, lb1);
    __syncthreads();
    bf16x8 af[4], bfr[4];
    for (int i = 0; i < 4; i++) af[i]  = *(const bf16x8*)&As[(ar + i * 16 + l15) * 32 + quad * 8];
    for (int j = 0; j < 4; j++) bfr[j] = *(const bf16x8*)&Bs[(bc + j * 16 + l15) * 32 + quad * 8];
    for (int i = 0; i < 4; i++)
      for (int j = 0; j < 4; j++)
        acc[i][j] = __builtin_amdgcn_mfma_f32_16x16x32_bf16(af[i], bfr[j], acc[i][j], 0, 0, 0);
    __syncthreads();
  }
  int which = n0 >> 10;  // block-uniform: 0=q 1=k 2=v
  u16* dst = which == 0 ? qb : (which == 1 ? kb : vb);
  float qs = which == 0 ? 0.045112882054311f : 1.0f;  // (1/32)*log2(e)
  for (int i = 0; i < 4; i++)
    for (int j = 0; j < 4; j++) {
      int o = n0 + bc + j * 16 + l15;
      int h = (o & 1023) >> 6, d = o & 63;
      for (int r = 0; r < 4; r++) {
        int m = m0 + ar + i * 16 + quad * 4 + r;
        int b = m >> 11, l = m & 2047;
        dst[((b * 16 + h) * 2048 + l) * 64 + d] = f2bf(acc[i][j][r] * qs);
      }
    }
}

// v[bh][l][d] -> vt[bh][d][l]
__global__ __launch_bounds__(256) void transpose_v_kernel(const u16* __restrict__ vb,
                                                          u16* __restrict__ vtb) {
  __shared__ alignas(16) u16 T[64 * 72];
  int lt = blockIdx.x, bh = blockIdx.y;
  int t = threadIdx.x;
  for (int ld = 0; ld < 2; ld++) {
    int idx = ld * 256 + t;
    int l = idx >> 3, d0 = (idx & 7) * 8;
    uint4 v = *(const uint4*)(vb + (bh * 2048 + lt * 64 + l) * 64 + d0);
    *(uint4*)&T[l * 72 + d0] = v;
  }
  __syncthreads();
  for (int ld = 0; ld < 2; ld++) {
    int idx = ld * 256 + t;
    int d = idx >> 3, l0 = (idx & 7) * 8;
    union { u16 us[8]; uint4 v; } tmp;
    for (int i2 = 0; i2 < 8; i2++) tmp.us[i2] = T[(l0 + i2) * 72 + d];
    *(uint4*)(vtb + (bh * 64 + d) * 2048 + lt * 64 + l0) = tmp.v;
  }
}

// Flash attention v4: 128 threads = 2 waves x 32 q-rows; 64-row q-tile;
// grid 32x32 = 1024 blocks = 4 independent blocks/CU (LDS exactly 40 KB).
// K/V: LDS dbuf DMA (xor-swizzled source), 1 barrier/kt.
// P: 64x64 stride-64 slab unioned with Q staging; XOR block-swizzle keyed on
// row bits {0,2,3} -> write addrs = 2 lane bases + immediates; b128 reads
// hit 8 dwords/bank (conflict-free). Softmax denom on MFMA pipe (ones-column).
__global__ __launch_bounds__(128, 2) void flash_kernel(const u16* __restrict__ qb,
                                                       const u16* __restrict__ kb,
                                                       const u16* __restrict__ vtb,
                                                       u16* __restrict__ ob) {
  __shared__ alignas(16) u16 Ks[2][64 * 64];
  __shared__ alignas(16) u16 Vts[2][64 * 64];
  __shared__ alignas(16) u16 QP[64 * 64];   // Q staging, then P (swizzled stride-64)
  int qt = blockIdx.x, bh = blockIdx.y;
  int b = bh >> 4, h = bh & 15;
  int tid = threadIdx.x, wave = tid >> 6, lane = tid & 63, quad = lane >> 4, l15 = lane & 15;
  int xw = l15 & 7;
  int q0 = qt * 64;
  const u16* qg = qb + (bh * 2048 + q0) * 64;
  const u16* kgb = kb + bh * 2048 * 64;
  const u16* vgb = vtb + bh * 64 * 2048;

  // stage Q (xor-swizzled source) into QP; K/V tile 0 into buffer 0
  for (int it = 0; it < 4; it++) {
    int idx = it * 128 + tid;
    int row = idx >> 3, blk = (idx & 7) ^ (row & 7);
    gld16(qg + row * 64 + blk * 8, &QP[idx * 8]);
    gld16(kgb + row * 64 + blk * 8, &Ks[0][idx * 8]);
    gld16(vgb + row * 2048 + blk * 8, &Vts[0][idx * 8]);
  }
  __syncthreads();

  // Q fragments: rows wave*32 + i*16 + l15 (row&7 == xw)
  bf16x8 aq[2][2];
  for (int i = 0; i < 2; i++) {
    int row = wave * 32 + i * 16 + l15;
    aq[i][0] = *(const bf16x8*)&QP[row * 64 + ((quad ^ xw) * 8)];
    aq[i][1] = *(const bf16x8*)&QP[row * 64 + (((4 + quad) ^ xw) * 8)];
  }
  __syncthreads();  // Q in regs; QP becomes the P slab (wave-private rows)

  bf16x8 vone;
  for (int e = 0; e < 8; e++) vone[e] = (__bf16)1.0f;
  f32x4 z = {0.f, 0.f, 0.f, 0.f};
  f32x4 o_[2][4], o4[2];
  for (int i = 0; i < 2; i++) { for (int j = 0; j < 4; j++) o_[i][j] = z; o4[i] = z; }

  int blkA = (quad ^ xw) * 8;        // K/V frag block offsets (cols 0-31)
  int blkB = ((4 + quad) ^ xw) * 8;  // cols 32-63

  // P swizzle: elem(row,col) at row*64 + (col&7) + 8*((col>>3) ^ key(row)),
  // key(row) = 4*(row&1) | 2*((row>>2)&1) | ((row>>3)&1).
  // Write side: row = wave*32+quad*4+ i*16+r, col = j*16+l15 ->
  //   key bits: 4*(r&1) [literal] | 2*(quad&1) | (quad>>1)  [lane bases]
  int pb0 = (l15 >> 3) ^ (quad >> 1);
  int wb = (wave * 32 + quad * 4) * 64 + (l15 & 7) + 8 * pb0;
  u16* pwe = &QP[wb + 16 * (quad & 1)];        // j even
  u16* pwo = &QP[wb + 16 * (1 - (quad & 1))];  // j odd
  // Read side: row = wave*32 + i*16 + l15 -> key from l15 bits {0,2,3}
  int keyr = 4 * (l15 & 1) + 2 * ((l15 >> 2) & 1) + (l15 >> 3);
  const u16* pr0 = &QP[(wave * 32 + l15) * 64 + 8 * (quad ^ keyr)];
  const u16* pr1 = &QP[(wave * 32 + l15) * 64 + 8 * ((4 + quad) ^ keyr)];

  for (int kt = 0; kt < 32; kt++) {
    int cur = kt & 1;
    if (kt < 31) {  // DMA-prefetch next K/V tile into alternate buffer
      int nxt = cur ^ 1;
      for (int it = 0; it < 4; it++) {
        int idx = it * 128 + tid;
        int row = idx >> 3, blk = (idx & 7) ^ (row & 7);
        gld16(kgb + (kt + 1) * 4096 + row * 64 + blk * 8, &Ks[nxt][idx * 8]);
        gld16(vgb + row * 2048 + (kt + 1) * 64 + blk * 8, &Vts[nxt][idx * 8]);
      }
    }
    const u16* ks = Ks[cur];
    const u16* vs = Vts[cur];
    bf16x8 bk0[4], bk1[4];
    for (int j = 0; j < 4; j++) {
      int ro = (j * 16 + l15) * 64;
      bk0[j] = *(const bf16x8*)&ks[ro + blkA];
      bk1[j] = *(const bf16x8*)&ks[ro + blkB];
    }
    for (int i = 0; i < 2; i++) {
      f32x4 s[4];
      for (int j = 0; j < 4; j++) {
        s[j] = __builtin_amdgcn_mfma_f32_16x16x32_bf16(aq[i][0], bk0[j], z, 0, 0, 0);
        s[j] = __builtin_amdgcn_mfma_f32_16x16x32_bf16(aq[i][1], bk1[j], s[j], 0, 0, 0);
      }
      // exp2 (Q pre-scaled) + round-half-up bf16 hi-store to swizzled P
      for (int j = 0; j < 4; j++)
        for (int r = 0; r < 4; r++) {
          float p = __builtin_amdgcn_exp2f(s[j][r]);
          unsigned u = __float_as_uint(p) + 0x8000u;
          u16* base = (j & 1) ? pwo : pwe;
          base[(i * 16 + r) * 64 + 32 * ((j >> 1) ^ (r & 1))] = (u16)(u >> 16);
        }
    }
    bf16x8 bv0[4], bv1[4];
    for (int j = 0; j < 4; j++) {
      int ro = (j * 16 + l15) * 64;
      bv0[j] = *(const bf16x8*)&vs[ro + blkA];
      bv1[j] = *(const bf16x8*)&vs[ro + blkB];
    }
    for (int i = 0; i < 2; i++) {
      bf16x8 ap0 = *(const bf16x8*)&pr0[i * 1024];
      bf16x8 ap1 = *(const bf16x8*)&pr1[i * 1024];
      for (int j = 0; j < 4; j++) {
        o_[i][j] = __builtin_amdgcn_mfma_f32_16x16x32_bf16(ap0, bv0[j], o_[i][j], 0, 0, 0);
        o_[i][j] = __builtin_amdgcn_mfma_f32_16x16x32_bf16(ap1, bv1[j], o_[i][j], 0, 0, 0);
      }
      o4[i] = __builtin_amdgcn_mfma_f32_16x16x32_bf16(ap0, vone, o4[i], 0, 0, 0);
      o4[i] = __builtin_amdgcn_mfma_f32_16x16x32_bf16(ap1, vone, o4[i], 0, 0, 0);
    }
    __syncthreads();  // drains next-tile DMA; fences cur K/V reuse
  }
  for (int i = 0; i < 2; i++)
    for (int j = 0; j < 4; j++) {
      int c = h * 64 + j * 16 + l15;
      for (int r = 0; r < 4; r++) {
        int q = q0 + wave * 32 + i * 16 + quad * 4 + r;
        ob[(b * 2048 + q) * 1024 + c] = f2bf(o_[i][j][r] / o4[i][r]);
      }
    }
}

// out[M,N] = A[M,K] * B[N,K]^T + bias[N], fp32 out. 128x64 tile -> grid 512 (2/CU).
__global__ __launch_bounds__(256) void gemm_out_kernel(const u16* __restrict__ A,
                                                       const u16* __restrict__ Bw,
                                                       const float* __restrict__ bias,
                                                       float* __restrict__ out) {
  __shared__ alignas(16) u16 As[128 * 32];
  __shared__ alignas(16) u16 Bs[64 * 32];
  const int K = 1024;
  int tid = threadIdx.x, wave = tid >> 6, lane = tid & 63, quad = lane >> 4, l15 = lane & 15;
  int m0 = blockIdx.y * 128, n0 = blockIdx.x * 64;
  f32x4 z = {0.f, 0.f, 0.f, 0.f};
  f32x4 acc[4][2];
  for (int i = 0; i < 4; i++) for (int j = 0; j < 2; j++) acc[i][j] = z;
  int r0 = tid >> 2, ko = (tid & 3) * 8;
  const u16* ga0 = A + (m0 + r0) * K + ko;
  const u16* ga1 = A + (m0 + r0 + 64) * K + ko;
  const u16* gb0 = Bw + (n0 + r0) * K + ko;
  u16 *la0 = &As[tid * 8], *la1 = &As[(256 + tid) * 8];
  u16 *lb0 = &Bs[tid * 8];
  int ar = (wave & 1) * 64, bc = (wave >> 1) * 32;
  for (int k0 = 0; k0 < K; k0 += 32) {
    gld16(ga0 + k0, la0); gld16(ga1 + k0, la1);
    if (r0 < 64) gld16(gb0 + k0, lb0);
    __syncthreads();
    bf16x8 af[4], bfr[2];
    for (int i = 0; i < 4; i++) af[i]  = *(const bf16x8*)&As[(ar + i * 16 + l15) * 32 + quad * 8];
    for (int j = 0; j < 2; j++) bfr[j] = *(const bf16x8*)&Bs[(bc + j * 16 + l15) * 32 + quad * 8];
    for (int i = 0; i < 4; i++)
      for (int j = 0; j < 2; j++)
        acc[i][j] = __builtin_amdgcn_mfma_f32_16x16x32_bf16(af[i], bfr[j], acc[i][j], 0, 0, 0);
    __syncthreads();
  }
  for (int i = 0; i < 4; i++)
    for (int j = 0; j < 2; j++) {
      int o = n0 + bc + j * 16 + l15;
      float bo = bias[o];
      for (int r = 0; r < 4; r++) {
        int m = m0 + ar + i * 16 + quad * 4 + r;
        out[m * 1024 + o] = acc[i][j][r] + bo;
      }
    }
}

extern "C" void kernel_launch(void* const* d_in, const int* in_sizes, int n_in,
                              void* d_out, int out_size, void* d_ws, size_t ws_size,
                              hipStream_t stream) {
  const float* x     = (const float*)d_in[0];
  const float* w_qkv = (const float*)d_in[1];
  const float* w_out = (const float*)d_in[2];
  const float* b_out = (const float*)d_in[3];
  float* out = (float*)d_out;
  u16* ws = (u16*)d_ws;
  u16* x_bf    = ws;             // 4194304
  u16* wqkv_bf = ws + 4194304;   // 3145728
  u16* wout_bf = ws + 7340032;   // 1048576
  u16* qb      = ws + 8388608;   // 4194304  [B,H,L,64] (pre-scaled)
  u16* kb      = ws + 12582912;  // 4194304  [B,H,L,64]
  u16* vb      = ws + 16777216;  // 4194304  [B,H,L,64]
  u16* vtb     = ws + 20971520;  // 4194304  [B,H,64,L]
  u16* ob      = ws + 25165824;  // 4194304  [B,L,C]

  cvt_all_kernel<<<8192, 256, 0, stream>>>(x, w_qkv, w_out, x_bf, wqkv_bf, wout_bf);
  gemm_qkv_kernel<<<dim3(24, 32), 256, 0, stream>>>(x_bf, wqkv_bf, qb, kb, vb);
  transpose_v_kernel<<<dim3(32, 32), 256, 0, stream>>>(vb, vtb);
  flash_kernel<<<dim3(32, 32), 128, 0, stream>>>(qb, kb, vtb, ob);
  gemm_out_kernel<<<dim3(16, 32), 256, 0, stream>>>(ob, wout_bf, b_out, out);
}